// Round 10
// baseline (282.559 us; speedup 1.0000x reference)
//
#include <hip/hip_runtime.h>

#define NN 100000   // nodes
#define NE 800000   // edges  (NE % 256 == 0)
#define NG 256      // graphs
#define CH 96       // in/hidden channels
#define OC 16       // out channels
#define NBLK 391    // ceil(NN/256)
#define TM 128      // gemm node tile (8 row-tiles of 16)
#define GBLK 782    // ceil(NN/TM)

typedef __attribute__((ext_vector_type(8))) short bf16x8;
typedef __attribute__((ext_vector_type(4))) float f32x4;

// ---------------- bf16 helpers ----------------
__device__ __forceinline__ unsigned short f2bf(float x) {
    unsigned u = __float_as_uint(x);
    return (unsigned short)((u + 0x7fffu + ((u >> 16) & 1u)) >> 16);  // RNE
}
__device__ __forceinline__ float bf2f(unsigned short h) {
    return __uint_as_float(((unsigned)h) << 16);
}
__device__ __forceinline__ void split8(const float4 a, const float4 b,
                                       bf16x8& hi, bf16x8& lo) {
    float v[8] = {a.x, a.y, a.z, a.w, b.x, b.y, b.z, b.w};
#pragma unroll
    for (int j = 0; j < 8; j++) {
        unsigned short h = f2bf(v[j]);
        hi[j] = (short)h;
        lo[j] = (short)f2bf(v[j] - bf2f(h));
    }
}
// 4 packed bf16 pairs (uint4) -> 8 floats
__device__ __forceinline__ void unpack8(uint4 v, float* f) {
    f[0] = __uint_as_float(v.x << 16); f[1] = __uint_as_float(v.x & 0xffff0000u);
    f[2] = __uint_as_float(v.y << 16); f[3] = __uint_as_float(v.y & 0xffff0000u);
    f[4] = __uint_as_float(v.z << 16); f[5] = __uint_as_float(v.z & 0xffff0000u);
    f[6] = __uint_as_float(v.w << 16); f[7] = __uint_as_float(v.w & 0xffff0000u);
}

// ---------------- init: zero padded cnt/gtot + W1,W2 prep + FOLDED W3'=W3@Wlin ----
// Layer 3 has no ReLU: pool/agg/linear are all linear and commute, so
// out = pool(agg(B2@W3)+b3)@Wlin = pool(agg(B2@(W3@Wlin))) + b3@Wlin.  (R6 WIN)
__global__ __launch_bounds__(256) void k_init(int* __restrict__ cntp,
                                              int* __restrict__ gtot,
                                              const float* __restrict__ W1,
                                              const float* __restrict__ W2,
                                              const float* __restrict__ W3,
                                              const float* __restrict__ b3,
                                              const float* __restrict__ Wlin,
                                              unsigned short* __restrict__ WH,
                                              unsigned short* __restrict__ WL,
                                              float* __restrict__ b3p) {
    int id = blockIdx.x * 256 + threadIdx.x;
    if (id < NN) {
        uint4 z = {0u, 0u, 0u, 0u};
        uint4* p = reinterpret_cast<uint4*>(&cntp[(size_t)id * 16]);
        p[0] = z; p[1] = z; p[2] = z; p[3] = z;
    }
    if (id == 0) *gtot = 0;
    if (id < 2 * CH * CH) {  // W1, W2 -> transposed split-bf16
        int w = id / (CH * CH);
        int r = id - w * (CH * CH);
        int k = r / CH;
        int n = r - k * CH;
        const float* Ws = (w == 0) ? W1 : W2;
        float v = Ws[k * CH + n];
        unsigned short h = f2bf(v);
        WH[w * CH * CH + n * CH + k] = h;
        WL[w * CH * CH + n * CH + k] = f2bf(v - bf2f(h));
    } else if (id < 2 * CH * CH + CH * OC) {  // W3' entry (k, oc)
        int r = id - 2 * CH * CH;
        int k = r / OC;
        int oc = r - k * OC;
        float v = 0.0f;
#pragma unroll 8
        for (int m = 0; m < CH; m++) v += W3[k * CH + m] * Wlin[m * OC + oc];
        unsigned short h = f2bf(v);
        WH[2 * CH * CH + oc * CH + k] = h;
        WL[2 * CH * CH + oc * CH + k] = f2bf(v - bf2f(h));
    } else if (id < 2 * CH * CH + CH * OC + OC) {  // b3' = b3 @ Wlin
        int oc = id - 2 * CH * CH - CH * OC;
        float v = 0.0f;
#pragma unroll 8
        for (int m = 0; m < CH; m++) v += b3[m] * Wlin[m * OC + oc];
        b3p[oc] = v;
    }
}

// ---------------- edge histogram, standalone (R5-proven shape, R4 padded counters)
// R9: hist runs BEFORE gemm1 now so dinv is ready for gemm1's A-row scaling.
__global__ __launch_bounds__(256) void k_hist(const int* __restrict__ dst,
                                              int* __restrict__ cntp,
                                              int* __restrict__ slot) {
    int e = blockIdx.x * 256 + threadIdx.x;
    slot[e] = atomicAdd(&cntp[(size_t)dst[e] * 16], 1);
}

// unordered CSR offsets: wave-scan + ONE atomic per wave + dinv + goff
__global__ __launch_bounds__(256) void k_offsets(const int* __restrict__ cntp,
                                                 int* __restrict__ cntc,
                                                 int* __restrict__ gtot,
                                                 int* __restrict__ off,
                                                 float* __restrict__ dinv,
                                                 const int* __restrict__ batch,
                                                 int* __restrict__ goff) {
    int i = blockIdx.x * 256 + threadIdx.x;
    int lane = threadIdx.x & 63;
    int c = (i < NN) ? cntp[(size_t)i * 16] : 0;

    // 64-lane inclusive scan
    int incl = c;
#pragma unroll
    for (int d = 1; d < 64; d <<= 1) {
        int t = __shfl_up(incl, d);
        if (lane >= d) incl += t;
    }
    int total = __shfl(incl, 63);
    int base = 0;
    if (lane == 63) base = atomicAdd(gtot, total);
    base = __shfl(base, 63);

    if (i >= NN) return;
    cntc[i] = c;
    off[i] = base + incl - c;
    dinv[i] = rsqrtf((float)c + 1.0f);
    int b = batch[i];
    int bp = (i > 0) ? batch[i - 1] : -1;
    for (int g = bp + 1; g <= b; g++) goff[g] = i;
    if (i == NN - 1)
        for (int g = b + 1; g <= NG; g++) goff[g] = NN;
}

// ---------------- front2: gemm-1 with dinv-scaled A (blocks < GBLK) || CSR build --
// R9: every H row is pre-scaled by dinv[row] (gemm1: on the fp32 A-load; gemm2/3:
// in the fp32 epilogue BEFORE f2bf — zero extra roundings). The per-edge coef
// dinv[s]*dinv[d] then reduces to a single dinv[d] at aggregate end, so packed
// carries ONLY the src index (4B) and build loses its random dinv[s] gather.
// R5 lesson (overlap is worth ~14us) preserved: gemm1 now overlaps build.
__global__ __launch_bounds__(256) void k_front2(const float* __restrict__ X,
                                                const unsigned short* __restrict__ WH,
                                                const unsigned short* __restrict__ WL,
                                                const float* __restrict__ dinv,
                                                unsigned short* __restrict__ H,
                                                const int* __restrict__ src,
                                                const int* __restrict__ dst,
                                                const int* __restrict__ off,
                                                const int* __restrict__ slot,
                                                int* __restrict__ packed) {
    __shared__ __align__(16) unsigned short WsH[CH * CH];  // 18 KB
    __shared__ __align__(16) unsigned short WsL[CH * CH];  // 18 KB

    const int tid = threadIdx.x;

    if (blockIdx.x >= GBLK) {  // ---- build path: packed[pos] = src only ----
        int e = (blockIdx.x - GBLK) * 256 + tid;
        int d = dst[e];
        packed[off[d] + slot[e]] = src[e];
        return;
    }

    // ---- gemm-1 path: H' = (dinv.X)(fp32) @ W1, split-bf16 (3 MFMAs) ----
    const int n0 = blockIdx.x * TM;
    {
        const uint4* sH = reinterpret_cast<const uint4*>(WH);
        const uint4* sL = reinterpret_cast<const uint4*>(WL);
        uint4* dH = reinterpret_cast<uint4*>(WsH);
        uint4* dL = reinterpret_cast<uint4*>(WsL);
        for (int i = tid; i < CH * CH / 8; i += 256) {
            dH[i] = sH[i];
            dL[i] = sL[i];
        }
    }
    __syncthreads();

    const int lane = tid & 63;
    const int wave = tid >> 6;
    const int lrow = lane & 15;
    const int quad = lane >> 4;

    const float4* X4 = reinterpret_cast<const float4*>(X);

    f32x4 acc[2][6];
#pragma unroll
    for (int rt = 0; rt < 2; rt++)
#pragma unroll
        for (int ct = 0; ct < 6; ct++) acc[rt][ct] = (f32x4){0.f, 0.f, 0.f, 0.f};

    int arow[2];
    float dsc[2];
#pragma unroll
    for (int rt = 0; rt < 2; rt++) {
        arow[rt] = min(n0 + (wave * 2 + rt) * 16 + lrow, NN - 1);
        dsc[rt] = dinv[arow[rt]];
    }

#pragma unroll
    for (int kc = 0; kc < 3; kc++) {
        bf16x8 ahi[2], alo[2];
#pragma unroll
        for (int rt = 0; rt < 2; rt++) {
            int fo = (arow[rt] * CH + kc * 32 + quad * 8) >> 2;
            float4 a0 = X4[fo], b0 = X4[fo + 1];
            float s = dsc[rt];
            a0.x *= s; a0.y *= s; a0.z *= s; a0.w *= s;
            b0.x *= s; b0.y *= s; b0.z *= s; b0.w *= s;
            split8(a0, b0, ahi[rt], alo[rt]);
        }
#pragma unroll
        for (int ct = 0; ct < 6; ct++) {
            int bo = (ct * 16 + lrow) * CH + kc * 32 + quad * 8;
            bf16x8 bhi = *reinterpret_cast<const bf16x8*>(&WsH[bo]);
            bf16x8 blo = *reinterpret_cast<const bf16x8*>(&WsL[bo]);
#pragma unroll
            for (int rt = 0; rt < 2; rt++) {
                acc[rt][ct] = __builtin_amdgcn_mfma_f32_16x16x32_bf16(
                    alo[rt], bhi, acc[rt][ct], 0, 0, 0);
                acc[rt][ct] = __builtin_amdgcn_mfma_f32_16x16x32_bf16(
                    ahi[rt], blo, acc[rt][ct], 0, 0, 0);
                acc[rt][ct] = __builtin_amdgcn_mfma_f32_16x16x32_bf16(
                    ahi[rt], bhi, acc[rt][ct], 0, 0, 0);
            }
        }
    }

#pragma unroll
    for (int rt = 0; rt < 2; rt++) {
        int rbase = n0 + (wave * 2 + rt) * 16 + quad * 4;
#pragma unroll
        for (int ct = 0; ct < 6; ct++) {
            int col = ct * 16 + lrow;
#pragma unroll
            for (int r = 0; r < 4; r++) {
                int row = rbase + r;
                if (row < NN) H[(size_t)row * CH + col] = f2bf(acc[rt][ct][r]);
            }
        }
    }
}

// ---------------- MFMA GEMM (layer 2): H'(bf16) = dinv.(X(bf16) @ W) -------------
__global__ __launch_bounds__(256) void k_gemm_bf16(const unsigned short* __restrict__ X,
                                                   const unsigned short* __restrict__ WH,
                                                   const unsigned short* __restrict__ WL,
                                                   const float* __restrict__ dinv,
                                                   unsigned short* __restrict__ H) {
    __shared__ __align__(16) unsigned short WsH[CH * CH];
    __shared__ __align__(16) unsigned short WsL[CH * CH];

    const int tid = threadIdx.x;
    const int n0 = blockIdx.x * TM;

    {
        const uint4* sH = reinterpret_cast<const uint4*>(WH);
        const uint4* sL = reinterpret_cast<const uint4*>(WL);
        uint4* dH = reinterpret_cast<uint4*>(WsH);
        uint4* dL = reinterpret_cast<uint4*>(WsL);
        for (int i = tid; i < CH * CH / 8; i += 256) {
            dH[i] = sH[i];
            dL[i] = sL[i];
        }
    }
    __syncthreads();

    const int lane = tid & 63;
    const int wave = tid >> 6;
    const int lrow = lane & 15;
    const int quad = lane >> 4;

    f32x4 acc[2][6];
#pragma unroll
    for (int rt = 0; rt < 2; rt++)
#pragma unroll
        for (int ct = 0; ct < 6; ct++) acc[rt][ct] = (f32x4){0.f, 0.f, 0.f, 0.f};

    int arow[2];
#pragma unroll
    for (int rt = 0; rt < 2; rt++)
        arow[rt] = min(n0 + (wave * 2 + rt) * 16 + lrow, NN - 1);

#pragma unroll
    for (int kc = 0; kc < 3; kc++) {
        bf16x8 ahi[2];
#pragma unroll
        for (int rt = 0; rt < 2; rt++)
            ahi[rt] = *reinterpret_cast<const bf16x8*>(
                &X[(size_t)arow[rt] * CH + kc * 32 + quad * 8]);
#pragma unroll
        for (int ct = 0; ct < 6; ct++) {
            int bo = (ct * 16 + lrow) * CH + kc * 32 + quad * 8;
            bf16x8 bhi = *reinterpret_cast<const bf16x8*>(&WsH[bo]);
            bf16x8 blo = *reinterpret_cast<const bf16x8*>(&WsL[bo]);
#pragma unroll
            for (int rt = 0; rt < 2; rt++) {
                acc[rt][ct] = __builtin_amdgcn_mfma_f32_16x16x32_bf16(
                    ahi[rt], blo, acc[rt][ct], 0, 0, 0);
                acc[rt][ct] = __builtin_amdgcn_mfma_f32_16x16x32_bf16(
                    ahi[rt], bhi, acc[rt][ct], 0, 0, 0);
            }
        }
    }

#pragma unroll
    for (int rt = 0; rt < 2; rt++) {
        int rbase = n0 + (wave * 2 + rt) * 16 + quad * 4;
        float dv[4];
#pragma unroll
        for (int r = 0; r < 4; r++)
            dv[r] = (rbase + r < NN) ? dinv[rbase + r] : 0.0f;
#pragma unroll
        for (int ct = 0; ct < 6; ct++) {
            int col = ct * 16 + lrow;
#pragma unroll
            for (int r = 0; r < 4; r++) {
                int row = rbase + r;
                if (row < NN) H[(size_t)row * CH + col] = f2bf(acc[rt][ct][r] * dv[r]);
            }
        }
    }
}

// ---------------- layer-3 GEMM, folded: H3'(bf16, 16 cols) = dinv.(B2 @ W3') -----
__global__ __launch_bounds__(256) void k_gemm3(const unsigned short* __restrict__ X,
                                               const unsigned short* __restrict__ WH,
                                               const unsigned short* __restrict__ WL,
                                               const float* __restrict__ dinv,
                                               unsigned short* __restrict__ H3) {
    __shared__ __align__(16) unsigned short WsH[OC * CH];  // 3 KB
    __shared__ __align__(16) unsigned short WsL[OC * CH];  // 3 KB

    const int tid = threadIdx.x;
    const int n0 = blockIdx.x * TM;

    {
        const uint4* sH = reinterpret_cast<const uint4*>(WH);
        const uint4* sL = reinterpret_cast<const uint4*>(WL);
        uint4* dH = reinterpret_cast<uint4*>(WsH);
        uint4* dL = reinterpret_cast<uint4*>(WsL);
        for (int i = tid; i < OC * CH / 8; i += 256) {
            dH[i] = sH[i];
            dL[i] = sL[i];
        }
    }
    __syncthreads();

    const int lane = tid & 63;
    const int wave = tid >> 6;
    const int lrow = lane & 15;
    const int quad = lane >> 4;

    f32x4 acc[2];
#pragma unroll
    for (int rt = 0; rt < 2; rt++) acc[rt] = (f32x4){0.f, 0.f, 0.f, 0.f};

    int arow[2];
#pragma unroll
    for (int rt = 0; rt < 2; rt++)
        arow[rt] = min(n0 + (wave * 2 + rt) * 16 + lrow, NN - 1);

#pragma unroll
    for (int kc = 0; kc < 3; kc++) {
        bf16x8 ahi[2];
#pragma unroll
        for (int rt = 0; rt < 2; rt++)
            ahi[rt] = *reinterpret_cast<const bf16x8*>(
                &X[(size_t)arow[rt] * CH + kc * 32 + quad * 8]);
        int bo = lrow * CH + kc * 32 + quad * 8;
        bf16x8 bhi = *reinterpret_cast<const bf16x8*>(&WsH[bo]);
        bf16x8 blo = *reinterpret_cast<const bf16x8*>(&WsL[bo]);
#pragma unroll
        for (int rt = 0; rt < 2; rt++) {
            acc[rt] = __builtin_amdgcn_mfma_f32_16x16x32_bf16(ahi[rt], blo, acc[rt], 0, 0, 0);
            acc[rt] = __builtin_amdgcn_mfma_f32_16x16x32_bf16(ahi[rt], bhi, acc[rt], 0, 0, 0);
        }
    }

#pragma unroll
    for (int rt = 0; rt < 2; rt++) {
        int rbase = n0 + (wave * 2 + rt) * 16 + quad * 4;
#pragma unroll
        for (int r = 0; r < 4; r++) {
            int row = rbase + r;
            if (row < NN) H3[(size_t)row * OC + lrow] = f2bf(acc[rt][r] * dinv[row]);
        }
    }
}

// ---------------- per-dst aggregation (layers 1,2): 24 threads/node --------------
// Pair-split (R8) + clamped 4-deep (R7) kept. Coef-free gathers (H pre-scaled):
// a = dinv[d]*(sum_e H'[s] + H'[n]) + bias. ILP/TLP levers measured neutral ->
// random-line-throughput bound; do not re-tune the loop.
template <bool RELU>
__global__ __launch_bounds__(256) void k_aggregate(const int* __restrict__ off,
                                                   const int* __restrict__ cnt,
                                                   const int* __restrict__ packed,
                                                   const float* __restrict__ dinv,
                                                   const float* __restrict__ bias,
                                                   const unsigned short* __restrict__ H,
                                                   unsigned short* __restrict__ Bout) {
    int idx = blockIdx.x * 256 + threadIdx.x;  // NN*24
    if (idx >= NN * 24) return;
    int t2 = idx >> 1;        // n*12 + c8
    int h = idx & 1;
    int n = t2 / 12;
    int c8 = t2 - n * 12;     // 8 channels per pair
    int e0 = off[n];
    int c = cnt[n];
    int half = (c + 1) >> 1;
    int es = e0 + (h ? half : 0);
    int ee = h ? (e0 + c) : (e0 + half);

    const uint4* H8 = reinterpret_cast<const uint4*>(H);

    float a[8] = {0.f, 0.f, 0.f, 0.f, 0.f, 0.f, 0.f, 0.f};
    if (h == 0) {  // self-loop term H'[n] (already dinv[n]-scaled)
        float hf[8];
        unpack8(H8[(size_t)n * 12 + c8], hf);
#pragma unroll
        for (int j = 0; j < 8; j++) a[j] = hf[j];
    }

    int last = ee - 1;
    for (int e = es; e < ee; e += 4) {  // clamped always-4-deep gathers
        int i1 = min(e + 1, last);
        int i2 = min(e + 2, last);
        int i3 = min(e + 3, last);
        int s0 = packed[e];
        int s1 = packed[i1];
        int s2 = packed[i2];
        int s3 = packed[i3];
        float c1 = (e + 1 <= last) ? 1.0f : 0.0f;   // clamped dups contribute 0
        float c2 = (e + 2 <= last) ? 1.0f : 0.0f;
        float c3 = (e + 3 <= last) ? 1.0f : 0.0f;
        uint4 v0 = H8[(size_t)s0 * 12 + c8];
        uint4 v1 = H8[(size_t)s1 * 12 + c8];
        uint4 v2 = H8[(size_t)s2 * 12 + c8];
        uint4 v3 = H8[(size_t)s3 * 12 + c8];
        float f0[8], f1[8], f2[8], f3[8];
        unpack8(v0, f0); unpack8(v1, f1); unpack8(v2, f2); unpack8(v3, f3);
#pragma unroll
        for (int j = 0; j < 8; j++)
            a[j] += f0[j] + f1[j] * c1 + f2[j] * c2 + f3[j] * c3;
    }

    // pair combine (even/odd lanes -> never crosses a wave)
#pragma unroll
    for (int j = 0; j < 8; j++) a[j] += __shfl_xor(a[j], 1);

    if (h == 0) {
        float di = dinv[n];
        const float4* bias4 = reinterpret_cast<const float4*>(bias);
        float4 b0 = bias4[c8 * 2], b1 = bias4[c8 * 2 + 1];
        float bf[8] = {b0.x, b0.y, b0.z, b0.w, b1.x, b1.y, b1.z, b1.w};
#pragma unroll
        for (int j = 0; j < 8; j++) a[j] = a[j] * di + bf[j];
        if (RELU) {
#pragma unroll
            for (int j = 0; j < 8; j++) a[j] = fmaxf(a[j], 0.0f);
        }
        uint4 o;
        o.x = (unsigned)f2bf(a[0]) | ((unsigned)f2bf(a[1]) << 16);
        o.y = (unsigned)f2bf(a[2]) | ((unsigned)f2bf(a[3]) << 16);
        o.z = (unsigned)f2bf(a[4]) | ((unsigned)f2bf(a[5]) << 16);
        o.w = (unsigned)f2bf(a[6]) | ((unsigned)f2bf(a[7]) << 16);
        reinterpret_cast<uint4*>(Bout)[(size_t)n * 12 + c8] = o;
    }
}

// ---------------- layer-3 aggregation, 16 ch: 4 threads/node (pair-split) --------
__global__ __launch_bounds__(256) void k_agg16(const int* __restrict__ off,
                                               const int* __restrict__ cnt,
                                               const int* __restrict__ packed,
                                               const float* __restrict__ dinv,
                                               const unsigned short* __restrict__ H3,
                                               float* __restrict__ B3) {
    int idx = blockIdx.x * 256 + threadIdx.x;  // NN*4
    if (idx >= NN * 4) return;
    int n = idx >> 2;
    int rem = idx & 3;
    int c8 = rem >> 1;        // 8 channels per pair
    int h = rem & 1;
    int e0 = off[n];
    int c = cnt[n];
    int half = (c + 1) >> 1;
    int es = e0 + (h ? half : 0);
    int ee = h ? (e0 + c) : (e0 + half);

    const uint4* H8 = reinterpret_cast<const uint4*>(H3);

    float a[8] = {0.f, 0.f, 0.f, 0.f, 0.f, 0.f, 0.f, 0.f};
    if (h == 0) {
        float hf[8];
        unpack8(H8[(size_t)n * 2 + c8], hf);
#pragma unroll
        for (int j = 0; j < 8; j++) a[j] = hf[j];
    }

    int last = ee - 1;
    for (int e = es; e < ee; e += 4) {
        int i1 = min(e + 1, last);
        int i2 = min(e + 2, last);
        int i3 = min(e + 3, last);
        int s0 = packed[e];
        int s1 = packed[i1];
        int s2 = packed[i2];
        int s3 = packed[i3];
        float c1 = (e + 1 <= last) ? 1.0f : 0.0f;
        float c2 = (e + 2 <= last) ? 1.0f : 0.0f;
        float c3 = (e + 3 <= last) ? 1.0f : 0.0f;
        uint4 v0 = H8[(size_t)s0 * 2 + c8];
        uint4 v1 = H8[(size_t)s1 * 2 + c8];
        uint4 v2 = H8[(size_t)s2 * 2 + c8];
        uint4 v3 = H8[(size_t)s3 * 2 + c8];
        float f0[8], f1[8], f2[8], f3[8];
        unpack8(v0, f0); unpack8(v1, f1); unpack8(v2, f2); unpack8(v3, f3);
#pragma unroll
        for (int j = 0; j < 8; j++)
            a[j] += f0[j] + f1[j] * c1 + f2[j] * c2 + f3[j] * c3;
    }

#pragma unroll
    for (int j = 0; j < 8; j++) a[j] += __shfl_xor(a[j], 1);

    if (h == 0) {
        float di = dinv[n];
#pragma unroll
        for (int j = 0; j < 8; j++) a[j] *= di;
        float4* B4 = reinterpret_cast<float4*>(B3);
        B4[(size_t)n * 4 + c8 * 2 + 0] = make_float4(a[0], a[1], a[2], a[3]);
        B4[(size_t)n * 4 + c8 * 2 + 1] = make_float4(a[4], a[5], a[6], a[7]);
    }
}

// ---------------- final: per-graph mean of 16-ch fp32 rows + b3' -----------------
__global__ __launch_bounds__(256) void k_pool16(const int* __restrict__ goff,
                                                const float* __restrict__ B3,
                                                const float* __restrict__ b3p,
                                                float* __restrict__ out) {
    __shared__ float sh[16][16];
    int g = blockIdx.x;
    int t = threadIdx.x;
    int ch = t & 15;
    int nl = t >> 4;
    int s = goff[g];
    int e = goff[g + 1];

    float acc = 0.0f;
    for (int n = s + nl; n < e; n += 16) acc += B3[(size_t)n * OC + ch];
    sh[nl][ch] = acc;
    __syncthreads();

    if (t < OC) {
        float r = 0.0f;
#pragma unroll
        for (int j = 0; j < 16; j++) r += sh[j][t];
        out[g * OC + t] = r / fmaxf((float)(e - s), 1.0f) + b3p[t];
    }
}

// ---------------- launch ----------------
extern "C" void kernel_launch(void* const* d_in, const int* in_sizes, int n_in,
                              void* d_out, int out_size, void* d_ws, size_t ws_size,
                              hipStream_t stream) {
    const float* x = (const float*)d_in[0];
    const int* ei = (const int*)d_in[1];
    const int* src = ei;
    const int* dst = ei + NE;
    const int* batch = (const int*)d_in[2];
    const float* W1 = (const float*)d_in[3];
    const float* b1 = (const float*)d_in[4];
    const float* W2 = (const float*)d_in[5];
    const float* b2 = (const float*)d_in[6];
    const float* W3 = (const float*)d_in[7];
    const float* b3 = (const float*)d_in[8];
    const float* Wlin = (const float*)d_in[9];
    float* out = (float*)d_out;

    char* ws = (char*)d_ws;
    unsigned short* Ha = (unsigned short*)ws;  ws += (size_t)NN * CH * 2;  // 19.2 MB
    unsigned short* Hb = (unsigned short*)ws;  ws += (size_t)NN * CH * 2;  // 19.2 MB
    unsigned short* Bb = (unsigned short*)ws;  ws += (size_t)NN * CH * 2;  // 19.2 MB
    int* packed = (int*)ws;         ws += (size_t)NE * 4;        // 3.2 MB (src only)
    unsigned short* WH = (unsigned short*)ws;  ws += 3 * CH * CH * 2;  // 55 KB
    unsigned short* WL = (unsigned short*)ws;  ws += 3 * CH * CH * 2;
    float* dinv = (float*)ws;       ws += NN * 4;
    int* off = (int*)ws;            ws += NN * 4;
    int* goff = (int*)ws;           ws += 272 * 4;       // NG+1, padded
    int* cntc = (int*)ws;           ws += (NN + 4) * 4;  // compact cnt + gtot slot
    int* gtot = cntc + NN;
    float* b3p = (float*)ws;        ws += 64;            // folded bias (16 f32)
    // Aliases (all verified against kernel order):
    //  cntp (padded counters, 6.4 MB) = Hb: dead after k_offsets, Hb written by gemm2.
    //  slot = Bb: written by hist, last read by front2-build; Bb written by agg1 (after).
    //  H3 (bf16 16-ch, 3.2 MB) = Ha: Ha last read by agg1; gemm3 runs after.
    //  B3 (fp32 16-ch, 6.4 MB) = Hb: Hb last read by agg2; agg16 runs after.
    int* cntp = (int*)Hb;
    int* slot = (int*)Bb;
    unsigned short* H3 = Ha;
    float* B3 = (float*)Hb;

    // init -> hist -> offsets -> (gemm1 || build)
    k_init<<<NBLK, 256, 0, stream>>>(cntp, gtot, W1, W2, W3, b3, Wlin, WH, WL, b3p);
    k_hist<<<NE / 256, 256, 0, stream>>>(dst, cntp, slot);
    k_offsets<<<NBLK, 256, 0, stream>>>(cntp, cntc, gtot, off, dinv, batch, goff);
    k_front2<<<GBLK + NE / 256, 256, 0, stream>>>(x, WH, WL, dinv, Ha,
                                                  src, dst, off, slot, packed);

    const int ablk = (NN * 24 + 255) / 256;  // 24 threads/node

    // layer 1 aggregate: Ha' -> Bb (relu)
    k_aggregate<true><<<ablk, 256, 0, stream>>>(off, cntc, packed, dinv, b1, Ha, Bb);
    // layer 2: Bb -> Hb' -> Bb (relu)
    k_gemm_bf16<<<GBLK, 256, 0, stream>>>(Bb, WH + CH * CH, WL + CH * CH, dinv, Hb);
    k_aggregate<true><<<ablk, 256, 0, stream>>>(off, cntc, packed, dinv, b2, Hb, Bb);
    // layer 3 (folded with Wlin): Bb -> H3' (16 ch) -> B3 (fp32) -> out
    k_gemm3<<<GBLK, 256, 0, stream>>>(Bb, WH + 2 * CH * CH, WL + 2 * CH * CH, dinv, H3);
    k_agg16<<<(NN * 4 + 255) / 256, 256, 0, stream>>>(off, cntc, packed, dinv, H3, B3);
    k_pool16<<<NG, 256, 0, stream>>>(goff, B3, b3p, out);
}

// Round 11
// 279.912 us; speedup vs baseline: 1.0095x; 1.0095x over previous
//
#include <hip/hip_runtime.h>

#define NN 100000   // nodes
#define NE 800000   // edges  (NE % 256 == 0)
#define NG 256      // graphs
#define CH 96       // in/hidden channels
#define OC 16       // out channels
#define NBLK 391    // ceil(NN/256)
#define TM 128      // gemm node tile, layers 2/3
#define GBLK 782    // ceil(NN/TM)
#define FTM 256     // front gemm-1 tile (R11: halves W staging, 2x X-load MLP)
#define FBLK 391    // ceil(NN/FTM)

typedef __attribute__((ext_vector_type(8))) short bf16x8;
typedef __attribute__((ext_vector_type(4))) float f32x4;

// ---------------- bf16 helpers ----------------
__device__ __forceinline__ unsigned short f2bf(float x) {
    unsigned u = __float_as_uint(x);
    return (unsigned short)((u + 0x7fffu + ((u >> 16) & 1u)) >> 16);  // RNE
}
__device__ __forceinline__ float bf2f(unsigned short h) {
    return __uint_as_float(((unsigned)h) << 16);
}
__device__ __forceinline__ void split8(const float4 a, const float4 b,
                                       bf16x8& hi, bf16x8& lo) {
    float v[8] = {a.x, a.y, a.z, a.w, b.x, b.y, b.z, b.w};
#pragma unroll
    for (int j = 0; j < 8; j++) {
        unsigned short h = f2bf(v[j]);
        hi[j] = (short)h;
        lo[j] = (short)f2bf(v[j] - bf2f(h));
    }
}
// 4 packed bf16 pairs (uint4) -> 8 floats
__device__ __forceinline__ void unpack8(uint4 v, float* f) {
    f[0] = __uint_as_float(v.x << 16); f[1] = __uint_as_float(v.x & 0xffff0000u);
    f[2] = __uint_as_float(v.y << 16); f[3] = __uint_as_float(v.y & 0xffff0000u);
    f[4] = __uint_as_float(v.z << 16); f[5] = __uint_as_float(v.z & 0xffff0000u);
    f[6] = __uint_as_float(v.w << 16); f[7] = __uint_as_float(v.w & 0xffff0000u);
}

// ---------------- init: zero padded cnt/gtot + W1,W2 prep + FOLDED W3'=W3@Wlin ----
// Layer 3 has no ReLU: pool/agg/linear are all linear and commute, so
// out = pool(agg(B2@W3)+b3)@Wlin = pool(agg(B2@(W3@Wlin))) + b3@Wlin.  (R6 WIN)
__global__ __launch_bounds__(256) void k_init(int* __restrict__ cntp,
                                              int* __restrict__ gtot,
                                              const float* __restrict__ W1,
                                              const float* __restrict__ W2,
                                              const float* __restrict__ W3,
                                              const float* __restrict__ b3,
                                              const float* __restrict__ Wlin,
                                              unsigned short* __restrict__ WH,
                                              unsigned short* __restrict__ WL,
                                              float* __restrict__ b3p) {
    int id = blockIdx.x * 256 + threadIdx.x;
    if (id < NN) {
        uint4 z = {0u, 0u, 0u, 0u};
        uint4* p = reinterpret_cast<uint4*>(&cntp[(size_t)id * 16]);
        p[0] = z; p[1] = z; p[2] = z; p[3] = z;
    }
    if (id == 0) *gtot = 0;
    if (id < 2 * CH * CH) {  // W1, W2 -> transposed split-bf16
        int w = id / (CH * CH);
        int r = id - w * (CH * CH);
        int k = r / CH;
        int n = r - k * CH;
        const float* Ws = (w == 0) ? W1 : W2;
        float v = Ws[k * CH + n];
        unsigned short h = f2bf(v);
        WH[w * CH * CH + n * CH + k] = h;
        WL[w * CH * CH + n * CH + k] = f2bf(v - bf2f(h));
    } else if (id < 2 * CH * CH + CH * OC) {  // W3' entry (k, oc)
        int r = id - 2 * CH * CH;
        int k = r / OC;
        int oc = r - k * OC;
        float v = 0.0f;
#pragma unroll 8
        for (int m = 0; m < CH; m++) v += W3[k * CH + m] * Wlin[m * OC + oc];
        unsigned short h = f2bf(v);
        WH[2 * CH * CH + oc * CH + k] = h;
        WL[2 * CH * CH + oc * CH + k] = f2bf(v - bf2f(h));
    } else if (id < 2 * CH * CH + CH * OC + OC) {  // b3' = b3 @ Wlin
        int oc = id - 2 * CH * CH - CH * OC;
        float v = 0.0f;
#pragma unroll 8
        for (int m = 0; m < CH; m++) v += b3[m] * Wlin[m * OC + oc];
        b3p[oc] = v;
    }
}

// ---------------- front: gemm-1 (blocks < FBLK, FTM=256) + edge histogram -------
// R4/R8-proven structure (monolithic 36KB staging, gemm-first order, padded cntp,
// hist||gemm1 overlap worth ~14us — R5/R10 both measured losing it).
// R11: FTM=256 — 391 gemm blocks instead of 782: halves W L2 re-reads + staging
// prologues, doubles per-thread X-load MLP (8 float4s in flight per kc).
__global__ __launch_bounds__(256) void k_front(const float* __restrict__ X,
                                               const unsigned short* __restrict__ WH,
                                               const unsigned short* __restrict__ WL,
                                               unsigned short* __restrict__ H,
                                               const int* __restrict__ dst,
                                               int* __restrict__ cntp,
                                               int* __restrict__ slot) {
    __shared__ __align__(16) unsigned short WsH[CH * CH];  // 18 KB
    __shared__ __align__(16) unsigned short WsL[CH * CH];  // 18 KB

    const int tid = threadIdx.x;

    if (blockIdx.x >= FBLK) {  // ---- histogram path: padded counters ----
        int e = (blockIdx.x - FBLK) * 256 + tid;
        slot[e] = atomicAdd(&cntp[(size_t)dst[e] * 16], 1);
        return;
    }

    // ---- gemm-1 path: H = X(fp32) @ W1, split-bf16 (3 MFMAs) ----
    const int n0 = blockIdx.x * FTM;
    {
        const uint4* sH = reinterpret_cast<const uint4*>(WH);
        const uint4* sL = reinterpret_cast<const uint4*>(WL);
        uint4* dH = reinterpret_cast<uint4*>(WsH);
        uint4* dL = reinterpret_cast<uint4*>(WsL);
        for (int i = tid; i < CH * CH / 8; i += 256) {
            dH[i] = sH[i];
            dL[i] = sL[i];
        }
    }
    __syncthreads();

    const int lane = tid & 63;
    const int wave = tid >> 6;
    const int lrow = lane & 15;
    const int quad = lane >> 4;

    const float4* X4 = reinterpret_cast<const float4*>(X);

    f32x4 acc[4][6];
#pragma unroll
    for (int rt = 0; rt < 4; rt++)
#pragma unroll
        for (int ct = 0; ct < 6; ct++) acc[rt][ct] = (f32x4){0.f, 0.f, 0.f, 0.f};

    int arow[4];
#pragma unroll
    for (int rt = 0; rt < 4; rt++)
        arow[rt] = min(n0 + (wave * 4 + rt) * 16 + lrow, NN - 1);

#pragma unroll
    for (int kc = 0; kc < 3; kc++) {
        bf16x8 ahi[4], alo[4];
#pragma unroll
        for (int rt = 0; rt < 4; rt++) {
            int fo = (arow[rt] * CH + kc * 32 + quad * 8) >> 2;
            split8(X4[fo], X4[fo + 1], ahi[rt], alo[rt]);
        }
#pragma unroll
        for (int ct = 0; ct < 6; ct++) {
            int bo = (ct * 16 + lrow) * CH + kc * 32 + quad * 8;
            bf16x8 bhi = *reinterpret_cast<const bf16x8*>(&WsH[bo]);
            bf16x8 blo = *reinterpret_cast<const bf16x8*>(&WsL[bo]);
#pragma unroll
            for (int rt = 0; rt < 4; rt++) {
                acc[rt][ct] = __builtin_amdgcn_mfma_f32_16x16x32_bf16(
                    alo[rt], bhi, acc[rt][ct], 0, 0, 0);
                acc[rt][ct] = __builtin_amdgcn_mfma_f32_16x16x32_bf16(
                    ahi[rt], blo, acc[rt][ct], 0, 0, 0);
                acc[rt][ct] = __builtin_amdgcn_mfma_f32_16x16x32_bf16(
                    ahi[rt], bhi, acc[rt][ct], 0, 0, 0);
            }
        }
    }

#pragma unroll
    for (int rt = 0; rt < 4; rt++) {
        int rbase = n0 + (wave * 4 + rt) * 16 + quad * 4;
#pragma unroll
        for (int ct = 0; ct < 6; ct++) {
            int col = ct * 16 + lrow;
#pragma unroll
            for (int r = 0; r < 4; r++) {
                int row = rbase + r;
                if (row < NN) H[(size_t)row * CH + col] = f2bf(acc[rt][ct][r]);
            }
        }
    }
}

// unordered CSR offsets: wave-scan + ONE atomic per wave + dinv + goff
__global__ __launch_bounds__(256) void k_offsets(const int* __restrict__ cntp,
                                                 int* __restrict__ cntc,
                                                 int* __restrict__ gtot,
                                                 int* __restrict__ off,
                                                 float* __restrict__ dinv,
                                                 const int* __restrict__ batch,
                                                 int* __restrict__ goff) {
    int i = blockIdx.x * 256 + threadIdx.x;
    int lane = threadIdx.x & 63;
    int c = (i < NN) ? cntp[(size_t)i * 16] : 0;

    // 64-lane inclusive scan
    int incl = c;
#pragma unroll
    for (int d = 1; d < 64; d <<= 1) {
        int t = __shfl_up(incl, d);
        if (lane >= d) incl += t;
    }
    int total = __shfl(incl, 63);
    int base = 0;
    if (lane == 63) base = atomicAdd(gtot, total);
    base = __shfl(base, 63);

    if (i >= NN) return;
    cntc[i] = c;
    off[i] = base + incl - c;
    dinv[i] = rsqrtf((float)c + 1.0f);
    int b = batch[i];
    int bp = (i > 0) ? batch[i - 1] : -1;
    for (int g = bp + 1; g <= b; g++) goff[g] = i;
    if (i == NN - 1)
        for (int g = b + 1; g <= NG; g++) goff[g] = NN;
}

__global__ __launch_bounds__(256) void k_build(const int* __restrict__ src,
                                               const int* __restrict__ dst,
                                               const int* __restrict__ off,
                                               const int* __restrict__ slot,
                                               const float* __restrict__ dinv,
                                               float2* __restrict__ packed) {
    int e = blockIdx.x * 256 + threadIdx.x;
    int s = src[e];
    int d = dst[e];
    packed[off[d] + slot[e]] = make_float2(__int_as_float(s), dinv[s] * dinv[d]);
}

// ---------------- MFMA GEMM (layer 2): H(bf16) = X(bf16) @ W, LDS-staged W ---
__global__ __launch_bounds__(256) void k_gemm_bf16(const unsigned short* __restrict__ X,
                                                   const unsigned short* __restrict__ WH,
                                                   const unsigned short* __restrict__ WL,
                                                   unsigned short* __restrict__ H) {
    __shared__ __align__(16) unsigned short WsH[CH * CH];
    __shared__ __align__(16) unsigned short WsL[CH * CH];

    const int tid = threadIdx.x;
    const int n0 = blockIdx.x * TM;

    {
        const uint4* sH = reinterpret_cast<const uint4*>(WH);
        const uint4* sL = reinterpret_cast<const uint4*>(WL);
        uint4* dH = reinterpret_cast<uint4*>(WsH);
        uint4* dL = reinterpret_cast<uint4*>(WsL);
        for (int i = tid; i < CH * CH / 8; i += 256) {
            dH[i] = sH[i];
            dL[i] = sL[i];
        }
    }
    __syncthreads();

    const int lane = tid & 63;
    const int wave = tid >> 6;
    const int lrow = lane & 15;
    const int quad = lane >> 4;

    f32x4 acc[2][6];
#pragma unroll
    for (int rt = 0; rt < 2; rt++)
#pragma unroll
        for (int ct = 0; ct < 6; ct++) acc[rt][ct] = (f32x4){0.f, 0.f, 0.f, 0.f};

    int arow[2];
#pragma unroll
    for (int rt = 0; rt < 2; rt++)
        arow[rt] = min(n0 + (wave * 2 + rt) * 16 + lrow, NN - 1);

#pragma unroll
    for (int kc = 0; kc < 3; kc++) {
        bf16x8 ahi[2];
#pragma unroll
        for (int rt = 0; rt < 2; rt++)
            ahi[rt] = *reinterpret_cast<const bf16x8*>(
                &X[(size_t)arow[rt] * CH + kc * 32 + quad * 8]);
#pragma unroll
        for (int ct = 0; ct < 6; ct++) {
            int bo = (ct * 16 + lrow) * CH + kc * 32 + quad * 8;
            bf16x8 bhi = *reinterpret_cast<const bf16x8*>(&WsH[bo]);
            bf16x8 blo = *reinterpret_cast<const bf16x8*>(&WsL[bo]);
#pragma unroll
            for (int rt = 0; rt < 2; rt++) {
                acc[rt][ct] = __builtin_amdgcn_mfma_f32_16x16x32_bf16(
                    ahi[rt], blo, acc[rt][ct], 0, 0, 0);
                acc[rt][ct] = __builtin_amdgcn_mfma_f32_16x16x32_bf16(
                    ahi[rt], bhi, acc[rt][ct], 0, 0, 0);
            }
        }
    }

#pragma unroll
    for (int rt = 0; rt < 2; rt++) {
        int rbase = n0 + (wave * 2 + rt) * 16 + quad * 4;
#pragma unroll
        for (int ct = 0; ct < 6; ct++) {
            int col = ct * 16 + lrow;
#pragma unroll
            for (int r = 0; r < 4; r++) {
                int row = rbase + r;
                if (row < NN) H[(size_t)row * CH + col] = f2bf(acc[rt][ct][r]);
            }
        }
    }
}

// ---------------- layer-3 GEMM, folded: H3(bf16, 16 cols) = B2 @ W3' ----------
__global__ __launch_bounds__(256) void k_gemm3(const unsigned short* __restrict__ X,
                                               const unsigned short* __restrict__ WH,
                                               const unsigned short* __restrict__ WL,
                                               unsigned short* __restrict__ H3) {
    __shared__ __align__(16) unsigned short WsH[OC * CH];  // 3 KB
    __shared__ __align__(16) unsigned short WsL[OC * CH];  // 3 KB

    const int tid = threadIdx.x;
    const int n0 = blockIdx.x * TM;

    {
        const uint4* sH = reinterpret_cast<const uint4*>(WH);
        const uint4* sL = reinterpret_cast<const uint4*>(WL);
        uint4* dH = reinterpret_cast<uint4*>(WsH);
        uint4* dL = reinterpret_cast<uint4*>(WsL);
        for (int i = tid; i < OC * CH / 8; i += 256) {
            dH[i] = sH[i];
            dL[i] = sL[i];
        }
    }
    __syncthreads();

    const int lane = tid & 63;
    const int wave = tid >> 6;
    const int lrow = lane & 15;
    const int quad = lane >> 4;

    f32x4 acc[2];
#pragma unroll
    for (int rt = 0; rt < 2; rt++) acc[rt] = (f32x4){0.f, 0.f, 0.f, 0.f};

    int arow[2];
#pragma unroll
    for (int rt = 0; rt < 2; rt++)
        arow[rt] = min(n0 + (wave * 2 + rt) * 16 + lrow, NN - 1);

#pragma unroll
    for (int kc = 0; kc < 3; kc++) {
        bf16x8 ahi[2];
#pragma unroll
        for (int rt = 0; rt < 2; rt++)
            ahi[rt] = *reinterpret_cast<const bf16x8*>(
                &X[(size_t)arow[rt] * CH + kc * 32 + quad * 8]);
        int bo = lrow * CH + kc * 32 + quad * 8;
        bf16x8 bhi = *reinterpret_cast<const bf16x8*>(&WsH[bo]);
        bf16x8 blo = *reinterpret_cast<const bf16x8*>(&WsL[bo]);
#pragma unroll
        for (int rt = 0; rt < 2; rt++) {
            acc[rt] = __builtin_amdgcn_mfma_f32_16x16x32_bf16(ahi[rt], blo, acc[rt], 0, 0, 0);
            acc[rt] = __builtin_amdgcn_mfma_f32_16x16x32_bf16(ahi[rt], bhi, acc[rt], 0, 0, 0);
        }
    }

#pragma unroll
    for (int rt = 0; rt < 2; rt++) {
        int rbase = n0 + (wave * 2 + rt) * 16 + quad * 4;
#pragma unroll
        for (int r = 0; r < 4; r++) {
            int row = rbase + r;
            if (row < NN) H3[(size_t)row * OC + lrow] = f2bf(acc[rt][r]);
        }
    }
}

// ---------------- per-dst aggregation (layers 1,2): 24 threads/node --------------
// R8: pair-split halves the dependent-gather chain; R7: clamped always-4-deep.
// Three concurrency levers (deeper ILP, prefetch rotation, TLP split) all measured
// ~neutral -> random-line-throughput bound; do not re-tune this loop.
template <bool RELU>
__global__ __launch_bounds__(256) void k_aggregate(const int* __restrict__ off,
                                                   const int* __restrict__ cnt,
                                                   const float2* __restrict__ packed,
                                                   const float* __restrict__ dinv,
                                                   const float* __restrict__ bias,
                                                   const unsigned short* __restrict__ H,
                                                   unsigned short* __restrict__ Bout) {
    int idx = blockIdx.x * 256 + threadIdx.x;  // NN*24
    if (idx >= NN * 24) return;
    int t2 = idx >> 1;        // n*12 + c8
    int h = idx & 1;
    int n = t2 / 12;
    int c8 = t2 - n * 12;     // 8 channels per pair
    int e0 = off[n];
    int c = cnt[n];
    int half = (c + 1) >> 1;
    int es = e0 + (h ? half : 0);
    int ee = h ? (e0 + c) : (e0 + half);

    const uint4* H8 = reinterpret_cast<const uint4*>(H);

    float a[8] = {0.f, 0.f, 0.f, 0.f, 0.f, 0.f, 0.f, 0.f};
    if (h == 0) {  // self-loop + bias once per pair
        float hf[8];
        unpack8(H8[(size_t)n * 12 + c8], hf);
        float di = dinv[n];
        float d2 = di * di;
        const float4* bias4 = reinterpret_cast<const float4*>(bias);
        float4 b0 = bias4[c8 * 2], b1 = bias4[c8 * 2 + 1];
        float bf[8] = {b0.x, b0.y, b0.z, b0.w, b1.x, b1.y, b1.z, b1.w};
#pragma unroll
        for (int j = 0; j < 8; j++) a[j] = hf[j] * d2 + bf[j];
    }

    int last = ee - 1;
    for (int e = es; e < ee; e += 4) {  // clamped always-4-deep gathers
        int i1 = min(e + 1, last);
        int i2 = min(e + 2, last);
        int i3 = min(e + 3, last);
        float2 p0 = packed[e];
        float2 p1 = packed[i1];
        float2 p2 = packed[i2];
        float2 p3 = packed[i3];
        float c1 = (e + 1 <= last) ? p1.y : 0.0f;
        float c2 = (e + 2 <= last) ? p2.y : 0.0f;
        float c3 = (e + 3 <= last) ? p3.y : 0.0f;
        uint4 v0 = H8[(size_t)__float_as_int(p0.x) * 12 + c8];
        uint4 v1 = H8[(size_t)__float_as_int(p1.x) * 12 + c8];
        uint4 v2 = H8[(size_t)__float_as_int(p2.x) * 12 + c8];
        uint4 v3 = H8[(size_t)__float_as_int(p3.x) * 12 + c8];
        float f0[8], f1[8], f2[8], f3[8];
        unpack8(v0, f0); unpack8(v1, f1); unpack8(v2, f2); unpack8(v3, f3);
#pragma unroll
        for (int j = 0; j < 8; j++)
            a[j] += f0[j] * p0.y + f1[j] * c1 + f2[j] * c2 + f3[j] * c3;
    }

    // pair combine (even/odd lanes -> never crosses a wave)
#pragma unroll
    for (int j = 0; j < 8; j++) a[j] += __shfl_xor(a[j], 1);

    if (h == 0) {
        if (RELU) {
#pragma unroll
            for (int j = 0; j < 8; j++) a[j] = fmaxf(a[j], 0.0f);
        }
        uint4 o;
        o.x = (unsigned)f2bf(a[0]) | ((unsigned)f2bf(a[1]) << 16);
        o.y = (unsigned)f2bf(a[2]) | ((unsigned)f2bf(a[3]) << 16);
        o.z = (unsigned)f2bf(a[4]) | ((unsigned)f2bf(a[5]) << 16);
        o.w = (unsigned)f2bf(a[6]) | ((unsigned)f2bf(a[7]) << 16);
        reinterpret_cast<uint4*>(Bout)[(size_t)n * 12 + c8] = o;
    }
}

// ---------------- layer-3 aggregation, 16 ch: 4 threads/node (pair-split) --------
__global__ __launch_bounds__(256) void k_agg16(const int* __restrict__ off,
                                               const int* __restrict__ cnt,
                                               const float2* __restrict__ packed,
                                               const float* __restrict__ dinv,
                                               const unsigned short* __restrict__ H3,
                                               float* __restrict__ B3) {
    int idx = blockIdx.x * 256 + threadIdx.x;  // NN*4
    if (idx >= NN * 4) return;
    int n = idx >> 2;
    int rem = idx & 3;
    int c8 = rem >> 1;        // 8 channels per pair
    int h = rem & 1;
    int e0 = off[n];
    int c = cnt[n];
    int half = (c + 1) >> 1;
    int es = e0 + (h ? half : 0);
    int ee = h ? (e0 + c) : (e0 + half);

    const uint4* H8 = reinterpret_cast<const uint4*>(H3);

    float a[8] = {0.f, 0.f, 0.f, 0.f, 0.f, 0.f, 0.f, 0.f};
    if (h == 0) {
        float hf[8];
        unpack8(H8[(size_t)n * 2 + c8], hf);
        float di = dinv[n];
        float d2 = di * di;
#pragma unroll
        for (int j = 0; j < 8; j++) a[j] = hf[j] * d2;
    }

    int last = ee - 1;
    for (int e = es; e < ee; e += 4) {
        int i1 = min(e + 1, last);
        int i2 = min(e + 2, last);
        int i3 = min(e + 3, last);
        float2 p0 = packed[e];
        float2 p1 = packed[i1];
        float2 p2 = packed[i2];
        float2 p3 = packed[i3];
        float c1 = (e + 1 <= last) ? p1.y : 0.0f;
        float c2 = (e + 2 <= last) ? p2.y : 0.0f;
        float c3 = (e + 3 <= last) ? p3.y : 0.0f;
        uint4 v0 = H8[(size_t)__float_as_int(p0.x) * 2 + c8];
        uint4 v1 = H8[(size_t)__float_as_int(p1.x) * 2 + c8];
        uint4 v2 = H8[(size_t)__float_as_int(p2.x) * 2 + c8];
        uint4 v3 = H8[(size_t)__float_as_int(p3.x) * 2 + c8];
        float f0[8], f1[8], f2[8], f3[8];
        unpack8(v0, f0); unpack8(v1, f1); unpack8(v2, f2); unpack8(v3, f3);
#pragma unroll
        for (int j = 0; j < 8; j++)
            a[j] += f0[j] * p0.y + f1[j] * c1 + f2[j] * c2 + f3[j] * c3;
    }

#pragma unroll
    for (int j = 0; j < 8; j++) a[j] += __shfl_xor(a[j], 1);

    if (h == 0) {
        float4* B4 = reinterpret_cast<float4*>(B3);
        B4[(size_t)n * 4 + c8 * 2 + 0] = make_float4(a[0], a[1], a[2], a[3]);
        B4[(size_t)n * 4 + c8 * 2 + 1] = make_float4(a[4], a[5], a[6], a[7]);
    }
}

// ---------------- final: per-graph mean of 16-ch fp32 rows + b3' -----------------
__global__ __launch_bounds__(256) void k_pool16(const int* __restrict__ goff,
                                                const float* __restrict__ B3,
                                                const float* __restrict__ b3p,
                                                float* __restrict__ out) {
    __shared__ float sh[16][16];
    int g = blockIdx.x;
    int t = threadIdx.x;
    int ch = t & 15;
    int nl = t >> 4;
    int s = goff[g];
    int e = goff[g + 1];

    float acc = 0.0f;
    for (int n = s + nl; n < e; n += 16) acc += B3[(size_t)n * OC + ch];
    sh[nl][ch] = acc;
    __syncthreads();

    if (t < OC) {
        float r = 0.0f;
#pragma unroll
        for (int j = 0; j < 16; j++) r += sh[j][t];
        out[g * OC + t] = r / fmaxf((float)(e - s), 1.0f) + b3p[t];
    }
}

// ---------------- launch ----------------
extern "C" void kernel_launch(void* const* d_in, const int* in_sizes, int n_in,
                              void* d_out, int out_size, void* d_ws, size_t ws_size,
                              hipStream_t stream) {
    const float* x = (const float*)d_in[0];
    const int* ei = (const int*)d_in[1];
    const int* src = ei;
    const int* dst = ei + NE;
    const int* batch = (const int*)d_in[2];
    const float* W1 = (const float*)d_in[3];
    const float* b1 = (const float*)d_in[4];
    const float* W2 = (const float*)d_in[5];
    const float* b2 = (const float*)d_in[6];
    const float* W3 = (const float*)d_in[7];
    const float* b3 = (const float*)d_in[8];
    const float* Wlin = (const float*)d_in[9];
    float* out = (float*)d_out;

    char* ws = (char*)d_ws;
    unsigned short* Ha = (unsigned short*)ws;  ws += (size_t)NN * CH * 2;  // 19.2 MB
    unsigned short* Hb = (unsigned short*)ws;  ws += (size_t)NN * CH * 2;  // 19.2 MB
    unsigned short* Bb = (unsigned short*)ws;  ws += (size_t)NN * CH * 2;  // 19.2 MB
    float2* packed = (float2*)ws;   ws += (size_t)NE * 8;        // 6.4 MB
    unsigned short* WH = (unsigned short*)ws;  ws += 3 * CH * CH * 2;  // 55 KB
    unsigned short* WL = (unsigned short*)ws;  ws += 3 * CH * CH * 2;
    float* dinv = (float*)ws;       ws += NN * 4;
    int* off = (int*)ws;            ws += NN * 4;
    int* goff = (int*)ws;           ws += 272 * 4;       // NG+1, padded
    int* cntc = (int*)ws;           ws += (NN + 4) * 4;  // compact cnt + gtot slot
    int* gtot = cntc + NN;
    float* b3p = (float*)ws;        ws += 64;            // folded bias (16 f32)
    // Aliases (all verified against kernel order):
    //  cntp (padded counters, 6.4 MB) = Hb: dead after k_offsets, Hb written by gemm2.
    //  slot = Bb: last read by k_build; Bb written by agg1 (after).
    //  H3 (bf16 16-ch, 3.2 MB) = Ha: Ha last read by agg1; gemm3 runs after.
    //  B3 (fp32 16-ch, 6.4 MB) = Hb: Hb last read by agg2; agg16 runs after.
    int* cntp = (int*)Hb;
    int* slot = (int*)Bb;
    unsigned short* H3 = Ha;
    float* B3 = (float*)Hb;

    // init (zero padded cnt/gtot + W prep + folded W3'/b3'), front, offsets, build
    k_init<<<NBLK, 256, 0, stream>>>(cntp, gtot, W1, W2, W3, b3, Wlin, WH, WL, b3p);
    k_front<<<FBLK + NE / 256, 256, 0, stream>>>(x, WH, WL, Ha, dst, cntp, slot);
    k_offsets<<<NBLK, 256, 0, stream>>>(cntp, cntc, gtot, off, dinv, batch, goff);
    k_build<<<NE / 256, 256, 0, stream>>>(src, dst, off, slot, dinv, packed);

    const int ablk = (NN * 24 + 255) / 256;  // 24 threads/node

    // layer 1 aggregate: Ha -> Bb (relu)
    k_aggregate<true><<<ablk, 256, 0, stream>>>(off, cntc, packed, dinv, b1, Ha, Bb);
    // layer 2: Bb -> Hb -> Bb (relu)
    k_gemm_bf16<<<GBLK, 256, 0, stream>>>(Bb, WH + CH * CH, WL + CH * CH, Hb);
    k_aggregate<true><<<ablk, 256, 0, stream>>>(off, cntc, packed, dinv, b2, Hb, Bb);
    // layer 3 (folded with Wlin): Bb -> H3 (16 ch) -> B3 (fp32) -> out
    k_gemm3<<<GBLK, 256, 0, stream>>>(Bb, WH + 2 * CH * CH, WL + 2 * CH * CH, H3);
    k_agg16<<<(NN * 4 + 255) / 256, 256, 0, stream>>>(off, cntc, packed, dinv, H3, B3);
    k_pool16<<<NG, 256, 0, stream>>>(goff, B3, b3p, out);
}

// Round 12
// 268.597 us; speedup vs baseline: 1.0520x; 1.0421x over previous
//
#include <hip/hip_runtime.h>

#define NN 100000   // nodes
#define NE 800000   // edges  (NE % 256 == 0)
#define NG 256      // graphs
#define CH 96       // in/hidden channels
#define OC 16       // out channels
#define NBLK 391    // ceil(NN/256)
#define TM 128      // gemm node tile (8 row-tiles of 16)
#define GBLK 782    // ceil(NN/TM)

typedef __attribute__((ext_vector_type(8))) short bf16x8;
typedef __attribute__((ext_vector_type(4))) float f32x4;

// ---------------- bf16 helpers ----------------
__device__ __forceinline__ unsigned short f2bf(float x) {
    unsigned u = __float_as_uint(x);
    return (unsigned short)((u + 0x7fffu + ((u >> 16) & 1u)) >> 16);  // RNE
}
__device__ __forceinline__ float bf2f(unsigned short h) {
    return __uint_as_float(((unsigned)h) << 16);
}
__device__ __forceinline__ void split8(const float4 a, const float4 b,
                                       bf16x8& hi, bf16x8& lo) {
    float v[8] = {a.x, a.y, a.z, a.w, b.x, b.y, b.z, b.w};
#pragma unroll
    for (int j = 0; j < 8; j++) {
        unsigned short h = f2bf(v[j]);
        hi[j] = (short)h;
        lo[j] = (short)f2bf(v[j] - bf2f(h));
    }
}
// 4 packed bf16 pairs (uint4) -> 8 floats
__device__ __forceinline__ void unpack8(uint4 v, float* f) {
    f[0] = __uint_as_float(v.x << 16); f[1] = __uint_as_float(v.x & 0xffff0000u);
    f[2] = __uint_as_float(v.y << 16); f[3] = __uint_as_float(v.y & 0xffff0000u);
    f[4] = __uint_as_float(v.z << 16); f[5] = __uint_as_float(v.z & 0xffff0000u);
    f[6] = __uint_as_float(v.w << 16); f[7] = __uint_as_float(v.w & 0xffff0000u);
}

// ---------------- init: zero padded cnt/gtot + W1,W2 prep + FOLDED W3'=W3@Wlin ----
// Layer 3 has no ReLU: pool/agg/linear are all linear and commute, so
// out = pool(agg(B2@W3)+b3)@Wlin = pool(agg(B2@(W3@Wlin))) + b3@Wlin.  (R6 WIN)
__global__ __launch_bounds__(256) void k_init(int* __restrict__ cntp,
                                              int* __restrict__ gtot,
                                              const float* __restrict__ W1,
                                              const float* __restrict__ W2,
                                              const float* __restrict__ W3,
                                              const float* __restrict__ b3,
                                              const float* __restrict__ Wlin,
                                              unsigned short* __restrict__ WH,
                                              unsigned short* __restrict__ WL,
                                              float* __restrict__ b3p) {
    int id = blockIdx.x * 256 + threadIdx.x;
    if (id < NN) {
        uint4 z = {0u, 0u, 0u, 0u};
        uint4* p = reinterpret_cast<uint4*>(&cntp[(size_t)id * 16]);
        p[0] = z; p[1] = z; p[2] = z; p[3] = z;
    }
    if (id == 0) *gtot = 0;
    if (id < 2 * CH * CH) {  // W1, W2 -> transposed split-bf16
        int w = id / (CH * CH);
        int r = id - w * (CH * CH);
        int k = r / CH;
        int n = r - k * CH;
        const float* Ws = (w == 0) ? W1 : W2;
        float v = Ws[k * CH + n];
        unsigned short h = f2bf(v);
        WH[w * CH * CH + n * CH + k] = h;
        WL[w * CH * CH + n * CH + k] = f2bf(v - bf2f(h));
    } else if (id < 2 * CH * CH + CH * OC) {  // W3' entry (k, oc)
        int r = id - 2 * CH * CH;
        int k = r / OC;
        int oc = r - k * OC;
        float v = 0.0f;
#pragma unroll 8
        for (int m = 0; m < CH; m++) v += W3[k * CH + m] * Wlin[m * OC + oc];
        unsigned short h = f2bf(v);
        WH[2 * CH * CH + oc * CH + k] = h;
        WL[2 * CH * CH + oc * CH + k] = f2bf(v - bf2f(h));
    } else if (id < 2 * CH * CH + CH * OC + OC) {  // b3' = b3 @ Wlin
        int oc = id - 2 * CH * CH - CH * OC;
        float v = 0.0f;
#pragma unroll 8
        for (int m = 0; m < CH; m++) v += b3[m] * Wlin[m * OC + oc];
        b3p[oc] = v;
    }
}

// ---------------- front: gemm-1 (blocks < GBLK) + edge histogram (rest) --------
// R4/R8-proven structure. Lever ledger (do not retry): hist batching x(R1),
// occupancy x(R3), line-pad 0(R4), shadow-counters 0(R5); gemm1 chunked-staging
// x(R3), TM=256 x(R11: VGPR 60->132, occ 31->9%); schedule hist-first x(R1),
// split x(R5), hist->gemm1||build x(R10). TM=128 + 36KB monolithic + gemm-first
// fused is the measured optimum.
__global__ __launch_bounds__(256) void k_front(const float* __restrict__ X,
                                               const unsigned short* __restrict__ WH,
                                               const unsigned short* __restrict__ WL,
                                               unsigned short* __restrict__ H,
                                               const int* __restrict__ dst,
                                               int* __restrict__ cntp,
                                               int* __restrict__ slot) {
    __shared__ __align__(16) unsigned short WsH[CH * CH];  // 18 KB
    __shared__ __align__(16) unsigned short WsL[CH * CH];  // 18 KB

    const int tid = threadIdx.x;

    if (blockIdx.x >= GBLK) {  // ---- histogram path: padded counters ----
        int e = (blockIdx.x - GBLK) * 256 + tid;
        slot[e] = atomicAdd(&cntp[(size_t)dst[e] * 16], 1);
        return;
    }

    // ---- gemm-1 path: H = X(fp32) @ W1, split-bf16 (3 MFMAs) ----
    const int n0 = blockIdx.x * TM;
    {
        const uint4* sH = reinterpret_cast<const uint4*>(WH);
        const uint4* sL = reinterpret_cast<const uint4*>(WL);
        uint4* dH = reinterpret_cast<uint4*>(WsH);
        uint4* dL = reinterpret_cast<uint4*>(WsL);
        for (int i = tid; i < CH * CH / 8; i += 256) {
            dH[i] = sH[i];
            dL[i] = sL[i];
        }
    }
    __syncthreads();

    const int lane = tid & 63;
    const int wave = tid >> 6;
    const int lrow = lane & 15;
    const int quad = lane >> 4;

    const float4* X4 = reinterpret_cast<const float4*>(X);

    f32x4 acc[2][6];
#pragma unroll
    for (int rt = 0; rt < 2; rt++)
#pragma unroll
        for (int ct = 0; ct < 6; ct++) acc[rt][ct] = (f32x4){0.f, 0.f, 0.f, 0.f};

    int arow[2];
#pragma unroll
    for (int rt = 0; rt < 2; rt++)
        arow[rt] = min(n0 + (wave * 2 + rt) * 16 + lrow, NN - 1);

#pragma unroll
    for (int kc = 0; kc < 3; kc++) {
        bf16x8 ahi[2], alo[2];
#pragma unroll
        for (int rt = 0; rt < 2; rt++) {
            int fo = (arow[rt] * CH + kc * 32 + quad * 8) >> 2;
            split8(X4[fo], X4[fo + 1], ahi[rt], alo[rt]);
        }
#pragma unroll
        for (int ct = 0; ct < 6; ct++) {
            int bo = (ct * 16 + lrow) * CH + kc * 32 + quad * 8;
            bf16x8 bhi = *reinterpret_cast<const bf16x8*>(&WsH[bo]);
            bf16x8 blo = *reinterpret_cast<const bf16x8*>(&WsL[bo]);
#pragma unroll
            for (int rt = 0; rt < 2; rt++) {
                acc[rt][ct] = __builtin_amdgcn_mfma_f32_16x16x32_bf16(
                    alo[rt], bhi, acc[rt][ct], 0, 0, 0);
                acc[rt][ct] = __builtin_amdgcn_mfma_f32_16x16x32_bf16(
                    ahi[rt], blo, acc[rt][ct], 0, 0, 0);
                acc[rt][ct] = __builtin_amdgcn_mfma_f32_16x16x32_bf16(
                    ahi[rt], bhi, acc[rt][ct], 0, 0, 0);
            }
        }
    }

#pragma unroll
    for (int rt = 0; rt < 2; rt++) {
        int rbase = n0 + (wave * 2 + rt) * 16 + quad * 4;
#pragma unroll
        for (int ct = 0; ct < 6; ct++) {
            int col = ct * 16 + lrow;
#pragma unroll
            for (int r = 0; r < 4; r++) {
                int row = rbase + r;
                if (row < NN) H[(size_t)row * CH + col] = f2bf(acc[rt][ct][r]);
            }
        }
    }
}

// unordered CSR offsets: wave-scan + ONE atomic per wave + dinv + goff
__global__ __launch_bounds__(256) void k_offsets(const int* __restrict__ cntp,
                                                 int* __restrict__ cntc,
                                                 int* __restrict__ gtot,
                                                 int* __restrict__ off,
                                                 float* __restrict__ dinv,
                                                 const int* __restrict__ batch,
                                                 int* __restrict__ goff) {
    int i = blockIdx.x * 256 + threadIdx.x;
    int lane = threadIdx.x & 63;
    int c = (i < NN) ? cntp[(size_t)i * 16] : 0;

    // 64-lane inclusive scan
    int incl = c;
#pragma unroll
    for (int d = 1; d < 64; d <<= 1) {
        int t = __shfl_up(incl, d);
        if (lane >= d) incl += t;
    }
    int total = __shfl(incl, 63);
    int base = 0;
    if (lane == 63) base = atomicAdd(gtot, total);
    base = __shfl(base, 63);

    if (i >= NN) return;
    cntc[i] = c;
    off[i] = base + incl - c;
    dinv[i] = rsqrtf((float)c + 1.0f);
    int b = batch[i];
    int bp = (i > 0) ? batch[i - 1] : -1;
    for (int g = bp + 1; g <= b; g++) goff[g] = i;
    if (i == NN - 1)
        for (int g = b + 1; g <= NG; g++) goff[g] = NN;
}

__global__ __launch_bounds__(256) void k_build(const int* __restrict__ src,
                                               const int* __restrict__ dst,
                                               const int* __restrict__ off,
                                               const int* __restrict__ slot,
                                               const float* __restrict__ dinv,
                                               float2* __restrict__ packed) {
    int e = blockIdx.x * 256 + threadIdx.x;
    int s = src[e];
    int d = dst[e];
    packed[off[d] + slot[e]] = make_float2(__int_as_float(s), dinv[s] * dinv[d]);
}

// ---------------- MFMA GEMM (layer 2): H(bf16) = X(bf16) @ W, LDS-staged W ---
__global__ __launch_bounds__(256) void k_gemm_bf16(const unsigned short* __restrict__ X,
                                                   const unsigned short* __restrict__ WH,
                                                   const unsigned short* __restrict__ WL,
                                                   unsigned short* __restrict__ H) {
    __shared__ __align__(16) unsigned short WsH[CH * CH];
    __shared__ __align__(16) unsigned short WsL[CH * CH];

    const int tid = threadIdx.x;
    const int n0 = blockIdx.x * TM;

    {
        const uint4* sH = reinterpret_cast<const uint4*>(WH);
        const uint4* sL = reinterpret_cast<const uint4*>(WL);
        uint4* dH = reinterpret_cast<uint4*>(WsH);
        uint4* dL = reinterpret_cast<uint4*>(WsL);
        for (int i = tid; i < CH * CH / 8; i += 256) {
            dH[i] = sH[i];
            dL[i] = sL[i];
        }
    }
    __syncthreads();

    const int lane = tid & 63;
    const int wave = tid >> 6;
    const int lrow = lane & 15;
    const int quad = lane >> 4;

    f32x4 acc[2][6];
#pragma unroll
    for (int rt = 0; rt < 2; rt++)
#pragma unroll
        for (int ct = 0; ct < 6; ct++) acc[rt][ct] = (f32x4){0.f, 0.f, 0.f, 0.f};

    int arow[2];
#pragma unroll
    for (int rt = 0; rt < 2; rt++)
        arow[rt] = min(n0 + (wave * 2 + rt) * 16 + lrow, NN - 1);

#pragma unroll
    for (int kc = 0; kc < 3; kc++) {
        bf16x8 ahi[2];
#pragma unroll
        for (int rt = 0; rt < 2; rt++)
            ahi[rt] = *reinterpret_cast<const bf16x8*>(
                &X[(size_t)arow[rt] * CH + kc * 32 + quad * 8]);
#pragma unroll
        for (int ct = 0; ct < 6; ct++) {
            int bo = (ct * 16 + lrow) * CH + kc * 32 + quad * 8;
            bf16x8 bhi = *reinterpret_cast<const bf16x8*>(&WsH[bo]);
            bf16x8 blo = *reinterpret_cast<const bf16x8*>(&WsL[bo]);
#pragma unroll
            for (int rt = 0; rt < 2; rt++) {
                acc[rt][ct] = __builtin_amdgcn_mfma_f32_16x16x32_bf16(
                    ahi[rt], blo, acc[rt][ct], 0, 0, 0);
                acc[rt][ct] = __builtin_amdgcn_mfma_f32_16x16x32_bf16(
                    ahi[rt], bhi, acc[rt][ct], 0, 0, 0);
            }
        }
    }

#pragma unroll
    for (int rt = 0; rt < 2; rt++) {
        int rbase = n0 + (wave * 2 + rt) * 16 + quad * 4;
#pragma unroll
        for (int ct = 0; ct < 6; ct++) {
            int col = ct * 16 + lrow;
#pragma unroll
            for (int r = 0; r < 4; r++) {
                int row = rbase + r;
                if (row < NN) H[(size_t)row * CH + col] = f2bf(acc[rt][ct][r]);
            }
        }
    }
}

// ---------------- layer-3 GEMM, folded: H3(bf16, 16 cols) = B2 @ W3' ----------
__global__ __launch_bounds__(256) void k_gemm3(const unsigned short* __restrict__ X,
                                               const unsigned short* __restrict__ WH,
                                               const unsigned short* __restrict__ WL,
                                               unsigned short* __restrict__ H3) {
    __shared__ __align__(16) unsigned short WsH[OC * CH];  // 3 KB
    __shared__ __align__(16) unsigned short WsL[OC * CH];  // 3 KB

    const int tid = threadIdx.x;
    const int n0 = blockIdx.x * TM;

    {
        const uint4* sH = reinterpret_cast<const uint4*>(WH);
        const uint4* sL = reinterpret_cast<const uint4*>(WL);
        uint4* dH = reinterpret_cast<uint4*>(WsH);
        uint4* dL = reinterpret_cast<uint4*>(WsL);
        for (int i = tid; i < OC * CH / 8; i += 256) {
            dH[i] = sH[i];
            dL[i] = sL[i];
        }
    }
    __syncthreads();

    const int lane = tid & 63;
    const int wave = tid >> 6;
    const int lrow = lane & 15;
    const int quad = lane >> 4;

    f32x4 acc[2];
#pragma unroll
    for (int rt = 0; rt < 2; rt++) acc[rt] = (f32x4){0.f, 0.f, 0.f, 0.f};

    int arow[2];
#pragma unroll
    for (int rt = 0; rt < 2; rt++)
        arow[rt] = min(n0 + (wave * 2 + rt) * 16 + lrow, NN - 1);

#pragma unroll
    for (int kc = 0; kc < 3; kc++) {
        bf16x8 ahi[2];
#pragma unroll
        for (int rt = 0; rt < 2; rt++)
            ahi[rt] = *reinterpret_cast<const bf16x8*>(
                &X[(size_t)arow[rt] * CH + kc * 32 + quad * 8]);
        int bo = lrow * CH + kc * 32 + quad * 8;
        bf16x8 bhi = *reinterpret_cast<const bf16x8*>(&WsH[bo]);
        bf16x8 blo = *reinterpret_cast<const bf16x8*>(&WsL[bo]);
#pragma unroll
        for (int rt = 0; rt < 2; rt++) {
            acc[rt] = __builtin_amdgcn_mfma_f32_16x16x32_bf16(ahi[rt], blo, acc[rt], 0, 0, 0);
            acc[rt] = __builtin_amdgcn_mfma_f32_16x16x32_bf16(ahi[rt], bhi, acc[rt], 0, 0, 0);
        }
    }

#pragma unroll
    for (int rt = 0; rt < 2; rt++) {
        int rbase = n0 + (wave * 2 + rt) * 16 + quad * 4;
#pragma unroll
        for (int r = 0; r < 4; r++) {
            int row = rbase + r;
            if (row < NN) H3[(size_t)row * OC + lrow] = f2bf(acc[rt][r]);
        }
    }
}

// ---------------- per-dst aggregation (layers 1,2): 24 threads/node --------------
// R8: pair-split halves the dependent-gather chain; R7: clamped always-4-deep.
// Three concurrency levers (deeper ILP, prefetch rotation, TLP split) all measured
// ~neutral -> random-line-throughput bound; do not re-tune this loop.
template <bool RELU>
__global__ __launch_bounds__(256) void k_aggregate(const int* __restrict__ off,
                                                   const int* __restrict__ cnt,
                                                   const float2* __restrict__ packed,
                                                   const float* __restrict__ dinv,
                                                   const float* __restrict__ bias,
                                                   const unsigned short* __restrict__ H,
                                                   unsigned short* __restrict__ Bout) {
    int idx = blockIdx.x * 256 + threadIdx.x;  // NN*24
    if (idx >= NN * 24) return;
    int t2 = idx >> 1;        // n*12 + c8
    int h = idx & 1;
    int n = t2 / 12;
    int c8 = t2 - n * 12;     // 8 channels per pair
    int e0 = off[n];
    int c = cnt[n];
    int half = (c + 1) >> 1;
    int es = e0 + (h ? half : 0);
    int ee = h ? (e0 + c) : (e0 + half);

    const uint4* H8 = reinterpret_cast<const uint4*>(H);

    float a[8] = {0.f, 0.f, 0.f, 0.f, 0.f, 0.f, 0.f, 0.f};
    if (h == 0) {  // self-loop + bias once per pair
        float hf[8];
        unpack8(H8[(size_t)n * 12 + c8], hf);
        float di = dinv[n];
        float d2 = di * di;
        const float4* bias4 = reinterpret_cast<const float4*>(bias);
        float4 b0 = bias4[c8 * 2], b1 = bias4[c8 * 2 + 1];
        float bf[8] = {b0.x, b0.y, b0.z, b0.w, b1.x, b1.y, b1.z, b1.w};
#pragma unroll
        for (int j = 0; j < 8; j++) a[j] = hf[j] * d2 + bf[j];
    }

    int last = ee - 1;
    for (int e = es; e < ee; e += 4) {  // clamped always-4-deep gathers
        int i1 = min(e + 1, last);
        int i2 = min(e + 2, last);
        int i3 = min(e + 3, last);
        float2 p0 = packed[e];
        float2 p1 = packed[i1];
        float2 p2 = packed[i2];
        float2 p3 = packed[i3];
        float c1 = (e + 1 <= last) ? p1.y : 0.0f;
        float c2 = (e + 2 <= last) ? p2.y : 0.0f;
        float c3 = (e + 3 <= last) ? p3.y : 0.0f;
        uint4 v0 = H8[(size_t)__float_as_int(p0.x) * 12 + c8];
        uint4 v1 = H8[(size_t)__float_as_int(p1.x) * 12 + c8];
        uint4 v2 = H8[(size_t)__float_as_int(p2.x) * 12 + c8];
        uint4 v3 = H8[(size_t)__float_as_int(p3.x) * 12 + c8];
        float f0[8], f1[8], f2[8], f3[8];
        unpack8(v0, f0); unpack8(v1, f1); unpack8(v2, f2); unpack8(v3, f3);
#pragma unroll
        for (int j = 0; j < 8; j++)
            a[j] += f0[j] * p0.y + f1[j] * c1 + f2[j] * c2 + f3[j] * c3;
    }

    // pair combine (even/odd lanes -> never crosses a wave)
#pragma unroll
    for (int j = 0; j < 8; j++) a[j] += __shfl_xor(a[j], 1);

    if (h == 0) {
        if (RELU) {
#pragma unroll
            for (int j = 0; j < 8; j++) a[j] = fmaxf(a[j], 0.0f);
        }
        uint4 o;
        o.x = (unsigned)f2bf(a[0]) | ((unsigned)f2bf(a[1]) << 16);
        o.y = (unsigned)f2bf(a[2]) | ((unsigned)f2bf(a[3]) << 16);
        o.z = (unsigned)f2bf(a[4]) | ((unsigned)f2bf(a[5]) << 16);
        o.w = (unsigned)f2bf(a[6]) | ((unsigned)f2bf(a[7]) << 16);
        reinterpret_cast<uint4*>(Bout)[(size_t)n * 12 + c8] = o;
    }
}

// ---------------- layer-3 aggregation, 16 ch: 4 threads/node (pair-split) --------
__global__ __launch_bounds__(256) void k_agg16(const int* __restrict__ off,
                                               const int* __restrict__ cnt,
                                               const float2* __restrict__ packed,
                                               const float* __restrict__ dinv,
                                               const unsigned short* __restrict__ H3,
                                               float* __restrict__ B3) {
    int idx = blockIdx.x * 256 + threadIdx.x;  // NN*4
    if (idx >= NN * 4) return;
    int n = idx >> 2;
    int rem = idx & 3;
    int c8 = rem >> 1;        // 8 channels per pair
    int h = rem & 1;
    int e0 = off[n];
    int c = cnt[n];
    int half = (c + 1) >> 1;
    int es = e0 + (h ? half : 0);
    int ee = h ? (e0 + c) : (e0 + half);

    const uint4* H8 = reinterpret_cast<const uint4*>(H3);

    float a[8] = {0.f, 0.f, 0.f, 0.f, 0.f, 0.f, 0.f, 0.f};
    if (h == 0) {
        float hf[8];
        unpack8(H8[(size_t)n * 2 + c8], hf);
        float di = dinv[n];
        float d2 = di * di;
#pragma unroll
        for (int j = 0; j < 8; j++) a[j] = hf[j] * d2;
    }

    int last = ee - 1;
    for (int e = es; e < ee; e += 4) {
        int i1 = min(e + 1, last);
        int i2 = min(e + 2, last);
        int i3 = min(e + 3, last);
        float2 p0 = packed[e];
        float2 p1 = packed[i1];
        float2 p2 = packed[i2];
        float2 p3 = packed[i3];
        float c1 = (e + 1 <= last) ? p1.y : 0.0f;
        float c2 = (e + 2 <= last) ? p2.y : 0.0f;
        float c3 = (e + 3 <= last) ? p3.y : 0.0f;
        uint4 v0 = H8[(size_t)__float_as_int(p0.x) * 2 + c8];
        uint4 v1 = H8[(size_t)__float_as_int(p1.x) * 2 + c8];
        uint4 v2 = H8[(size_t)__float_as_int(p2.x) * 2 + c8];
        uint4 v3 = H8[(size_t)__float_as_int(p3.x) * 2 + c8];
        float f0[8], f1[8], f2[8], f3[8];
        unpack8(v0, f0); unpack8(v1, f1); unpack8(v2, f2); unpack8(v3, f3);
#pragma unroll
        for (int j = 0; j < 8; j++)
            a[j] += f0[j] * p0.y + f1[j] * c1 + f2[j] * c2 + f3[j] * c3;
    }

#pragma unroll
    for (int j = 0; j < 8; j++) a[j] += __shfl_xor(a[j], 1);

    if (h == 0) {
        float4* B4 = reinterpret_cast<float4*>(B3);
        B4[(size_t)n * 4 + c8 * 2 + 0] = make_float4(a[0], a[1], a[2], a[3]);
        B4[(size_t)n * 4 + c8 * 2 + 1] = make_float4(a[4], a[5], a[6], a[7]);
    }
}

// ---------------- final: per-graph mean of 16-ch fp32 rows + b3' -----------------
__global__ __launch_bounds__(256) void k_pool16(const int* __restrict__ goff,
                                                const float* __restrict__ B3,
                                                const float* __restrict__ b3p,
                                                float* __restrict__ out) {
    __shared__ float sh[16][16];
    int g = blockIdx.x;
    int t = threadIdx.x;
    int ch = t & 15;
    int nl = t >> 4;
    int s = goff[g];
    int e = goff[g + 1];

    float acc = 0.0f;
    for (int n = s + nl; n < e; n += 16) acc += B3[(size_t)n * OC + ch];
    sh[nl][ch] = acc;
    __syncthreads();

    if (t < OC) {
        float r = 0.0f;
#pragma unroll
        for (int j = 0; j < 16; j++) r += sh[j][t];
        out[g * OC + t] = r / fmaxf((float)(e - s), 1.0f) + b3p[t];
    }
}

// ---------------- launch ----------------
extern "C" void kernel_launch(void* const* d_in, const int* in_sizes, int n_in,
                              void* d_out, int out_size, void* d_ws, size_t ws_size,
                              hipStream_t stream) {
    const float* x = (const float*)d_in[0];
    const int* ei = (const int*)d_in[1];
    const int* src = ei;
    const int* dst = ei + NE;
    const int* batch = (const int*)d_in[2];
    const float* W1 = (const float*)d_in[3];
    const float* b1 = (const float*)d_in[4];
    const float* W2 = (const float*)d_in[5];
    const float* b2 = (const float*)d_in[6];
    const float* W3 = (const float*)d_in[7];
    const float* b3 = (const float*)d_in[8];
    const float* Wlin = (const float*)d_in[9];
    float* out = (float*)d_out;

    char* ws = (char*)d_ws;
    unsigned short* Ha = (unsigned short*)ws;  ws += (size_t)NN * CH * 2;  // 19.2 MB
    unsigned short* Hb = (unsigned short*)ws;  ws += (size_t)NN * CH * 2;  // 19.2 MB
    unsigned short* Bb = (unsigned short*)ws;  ws += (size_t)NN * CH * 2;  // 19.2 MB
    float2* packed = (float2*)ws;   ws += (size_t)NE * 8;        // 6.4 MB
    unsigned short* WH = (unsigned short*)ws;  ws += 3 * CH * CH * 2;  // 55 KB
    unsigned short* WL = (unsigned short*)ws;  ws += 3 * CH * CH * 2;
    float* dinv = (float*)ws;       ws += NN * 4;
    int* off = (int*)ws;            ws += NN * 4;
    int* goff = (int*)ws;           ws += 272 * 4;       // NG+1, padded
    int* cntc = (int*)ws;           ws += (NN + 4) * 4;  // compact cnt + gtot slot
    int* gtot = cntc + NN;
    float* b3p = (float*)ws;        ws += 64;            // folded bias (16 f32)
    // Aliases (all verified against kernel order):
    //  cntp (padded counters, 6.4 MB) = Hb: dead after k_offsets, Hb written by gemm2.
    //  slot = Bb: last read by k_build; Bb written by agg1 (after).
    //  H3 (bf16 16-ch, 3.2 MB) = Ha: Ha last read by agg1; gemm3 runs after.
    //  B3 (fp32 16-ch, 6.4 MB) = Hb: Hb last read by agg2; agg16 runs after.
    int* cntp = (int*)Hb;
    int* slot = (int*)Bb;
    unsigned short* H3 = Ha;
    float* B3 = (float*)Hb;

    // init (zero padded cnt/gtot + W prep + folded W3'/b3'), front, offsets, build
    k_init<<<NBLK, 256, 0, stream>>>(cntp, gtot, W1, W2, W3, b3, Wlin, WH, WL, b3p);
    k_front<<<GBLK + NE / 256, 256, 0, stream>>>(x, WH, WL, Ha, dst, cntp, slot);
    k_offsets<<<NBLK, 256, 0, stream>>>(cntp, cntc, gtot, off, dinv, batch, goff);
    k_build<<<NE / 256, 256, 0, stream>>>(src, dst, off, slot, dinv, packed);

    const int ablk = (NN * 24 + 255) / 256;  // 24 threads/node

    // layer 1 aggregate: Ha -> Bb (relu)
    k_aggregate<true><<<ablk, 256, 0, stream>>>(off, cntc, packed, dinv, b1, Ha, Bb);
    // layer 2: Bb -> Hb -> Bb (relu)
    k_gemm_bf16<<<GBLK, 256, 0, stream>>>(Bb, WH + CH * CH, WL + CH * CH, Hb);
    k_aggregate<true><<<ablk, 256, 0, stream>>>(off, cntc, packed, dinv, b2, Hb, Bb);
    // layer 3 (folded with Wlin): Bb -> H3 (16 ch) -> B3 (fp32) -> out
    k_gemm3<<<GBLK, 256, 0, stream>>>(Bb, WH + 2 * CH * CH, WL + 2 * CH * CH, H3);
    k_agg16<<<(NN * 4 + 255) / 256, 256, 0, stream>>>(off, cntc, packed, dinv, H3, B3);
    k_pool16<<<NG, 256, 0, stream>>>(goff, B3, b3p, out);
}